// Round 7
// baseline (27.749 us; speedup 1.0000x reference)
//
#include <hip/hip_runtime.h>
#include <hip/hip_bf16.h>

#define HOURS 24
#define MM 128
#define EE 128

typedef short bf16x8 __attribute__((ext_vector_type(8)));
typedef float f32x4 __attribute__((ext_vector_type(4)));

__device__ __forceinline__ unsigned short f2bfu(float f) {
    __hip_bfloat16 h = __float2bfloat16(f);
    return __builtin_bit_cast(unsigned short, h);
}
__device__ __forceinline__ float bfu2f(unsigned short u) {
    unsigned int x = ((unsigned int)u) << 16;
    return __builtin_bit_cast(float, x);
}
__device__ __forceinline__ unsigned int pack2(float a, float b) {
    return (unsigned int)f2bfu(a) | ((unsigned int)f2bfu(b) << 16);
}
// swizzled short-index of 16B unit `unit` in row `row` of a [*][128] bf16 tile
__device__ __forceinline__ int swz8(int row, int unit) {
    return row * 128 + (((unit ^ (row & 7)) & 15) << 3);
}
// scalar variant: short-index of element (row, col)
__device__ __forceinline__ int swzs(int row, int col) {
    return row * 128 + ((((col >> 3) ^ (row & 7)) & 15) << 3) + (col & 7);
}
// load 8 consecutive f32 from global, convert to bf16x8 fragment
__device__ __forceinline__ bf16x8 load_w_frag(const float* base) {
    float4 x = *(const float4*)base;
    float4 y = *(const float4*)(base + 4);
    union { unsigned int u[4]; bf16x8 v; } r;
    r.u[0] = pack2(x.x, x.y); r.u[1] = pack2(x.z, x.w);
    r.u[2] = pack2(y.x, y.y); r.u[3] = pack2(y.z, y.w);
    return r.v;
}

#define MFMA(a, b, c) __builtin_amdgcn_mfma_f32_16x16x32_bf16(a, b, c, 0, 0, 0)

// ---------------- prep: AT = (Wq^T Wk)^T and WvT = Wv^T, bf16, to workspace ----------
// 8 blocks x 256 thr; block g handles f-stripe [g*16, g*16+16)
__global__ __launch_bounds__(256) void k_prep(
    const float* __restrict__ Wq, const float* __restrict__ Wk,
    const float* __restrict__ Wv,
    short* __restrict__ ATws, short* __restrict__ WvTws)
{
    __shared__ alignas(16) short WqTl[128 * 128];   // Wq^T bf16, swz8
    __shared__ alignas(16) short WkTl[16 * 128];    // Wk^T stripe
    int f0 = blockIdx.x * 16;
    int tid = threadIdx.x;
#pragma unroll 4
    for (int it = 0; it < 64; ++it) {
        int idx = it * 256 + tid;
        int n = idx >> 7, e = idx & 127;
        WqTl[swzs(e, n)] = (short)f2bfu(Wq[n * 128 + e]);
    }
#pragma unroll
    for (int it = 0; it < 8; ++it) {
        int idx = it * 256 + tid;
        int n = idx >> 4, j = idx & 15;
        WkTl[swzs(j, n)] = (short)f2bfu(Wk[n * 128 + f0 + j]);
    }
#pragma unroll
    for (int it = 0; it < 8; ++it) {
        int idx = it * 256 + tid;
        int j = idx >> 7, e = idx & 127;
        WvTws[(f0 + j) * 128 + e] = (short)f2bfu(Wv[e * 128 + f0 + j]);
    }
    __syncthreads();
    int l = tid & 63, w = tid >> 6;
    int lr = l & 15, lg = l >> 4;
    bf16x8 af[4];
#pragma unroll
    for (int kf = 0; kf < 4; ++kf)
        af[kf] = *(const bf16x8*)&WkTl[swz8(lr, kf * 4 + lg)];
#pragma unroll
    for (int t2 = 0; t2 < 2; ++t2) {
        int et = 2 * w + t2;
        f32x4 acc = (f32x4){0.f, 0.f, 0.f, 0.f};
#pragma unroll
        for (int kf = 0; kf < 4; ++kf) {
            bf16x8 bf = *(const bf16x8*)&WqTl[swz8(et * 16 + lr, kf * 4 + lg)];
            acc = MFMA(af[kf], bf, acc);
        }
#pragma unroll
        for (int r = 0; r < 4; ++r)
            ATws[(f0 + lg * 4 + r) * 128 + et * 16 + lr] = (short)f2bfu(acc[r]);
    }
}

// ---------------- main: one block = (b, 16-candidate chunk), 512 thr = 8 waves ------
// P0: coefs + gather J      P1: tms/bsv + T1 = J.A (via AT) + CW = cand.Wv (via WvT)
// P2a: S = T1.J^T (regs) + CV = CW.J^T (hi/lo)   P2b: softmax -> P (over Jl)
// P3: G = CV.P^T ; epilogue ; direct store
__global__ __launch_bounds__(512) void k_main(
    const int* __restrict__ full_seq, const int* __restrict__ time_seq,
    const int* __restrict__ user, const int* __restrict__ posneg,
    const int* __restrict__ traj_len,
    const float* __restrict__ mat1, const float* __restrict__ mat2,
    const float* __restrict__ vecg,
    const float* __restrict__ emb_t, const float* __restrict__ emb_u,
    const float* __restrict__ emb_loc,
    const float* __restrict__ esl, const float* __restrict__ esu,
    const float* __restrict__ etl, const float* __restrict__ etu,
    const short* __restrict__ ATws, const short* __restrict__ WvTws,
    float* __restrict__ outp)
{
    __shared__ alignas(16) short Jl[128 * 128];    // J -> (after P2a) P   32KB
    __shared__ alignas(16) short T1l[128 * 128];   // 32KB
    __shared__ alignas(16) short CWl[16 * 128];    // 4KB
    __shared__ alignas(16) short CVh[16 * 128];    // 4KB
    __shared__ alignas(16) short CVm[16 * 128];    // 4KB
    __shared__ float tms[128], bsv[128], coef[8], PART[8][16];

    const int b = blockIdx.y, l0g = blockIdx.x * 16;
    const int tid = threadIdx.x;
    const int w = tid >> 6, l = tid & 63;
    const int lr = l & 15, lg = l >> 4;
    const int tl = traj_len[b];

    // ---- P0: coef (wave w computes coef[w]) + gather J ----
    {
        const float* tb4[4] = {esl, esu, etl, etu};
        const float* t = tb4[w >> 1];
        int row = w & 1;
        float v = t[row * 128 + l] + t[row * 128 + 64 + l];
#pragma unroll
        for (int off = 32; off >= 1; off >>= 1) v += __shfl_xor(v, off, 64);
        if (l == 0) coef[w] = v;
    }
    {
        int uid = user[b];
        const float4* Eu4 = (const float4*)(emb_u + (size_t)uid * 128);
#pragma unroll
        for (int it = 0; it < 8; ++it) {
            int i4 = it * 512 + tid;          // 4096 float4 units
            int mm = i4 >> 5, fq = i4 & 31;
            int t = time_seq[b * MM + mm];
            int tim = (t - 1) % HOURS + 1;
            int loc = full_seq[b * MM + mm];
            float4 a = ((const float4*)(emb_t + (size_t)tim * 128))[fq];
            float4 c = ((const float4*)(emb_loc + (size_t)loc * 128))[fq];
            float4 u = Eu4[fq];
            uint2 pk;
            pk.x = pack2(a.x + c.x + u.x, a.y + c.y + u.y);
            pk.y = pack2(a.z + c.z + u.z, a.w + c.w + u.w);
            *(uint2*)&Jl[swz8(mm, fq >> 1) + (fq & 1) * 4] = pk;
        }
    }
    __syncthreads();

    // ---- P1: tms/bsv + T1 (wave w -> f-tile w) + CW (wave w -> f-tile w) ----
    if (tid < 128) {
        int vv = (tid < tl) ? 1 : 0;
        float ssl = vv ? coef[1] : coef[0];
        float ssu = vv ? coef[3] : coef[2];
        float stl = vv ? coef[5] : coef[4];
        float stu = vv ? coef[7] : coef[6];
        tms[tid] = ssl + stl + (stu - stl) * 0.01f * vecg[b * MM + tid];
        bsv[tid] = (ssu - ssl) * 0.01f;
    }
    {
        bf16x8 atf[4];
#pragma unroll
        for (int kf = 0; kf < 4; ++kf)
            atf[kf] = *(const bf16x8*)&ATws[(w * 16 + lr) * 128 + kf * 32 + lg * 8];
        int n0 = w * 16 + lg * 4;
#pragma unroll
        for (int mt = 0; mt < 8; ++mt) {
            f32x4 acc = (f32x4){0.f, 0.f, 0.f, 0.f};
#pragma unroll
            for (int kf = 0; kf < 4; ++kf) {
                bf16x8 bj = *(const bf16x8*)&Jl[swz8(mt * 16 + lr, kf * 4 + lg)];
                acc = MFMA(atf[kf], bj, acc);
            }
            uint2 pk;
            pk.x = pack2(acc[0], acc[1]);
            pk.y = pack2(acc[2], acc[3]);
            *(uint2*)&T1l[swz8(mt * 16 + lr, n0 >> 3) + (n0 & 7)] = pk;
        }
        int p = posneg[b * MM + l0g + lr];
        bf16x8 ca[4], wvf[4];
#pragma unroll
        for (int kf = 0; kf < 4; ++kf) {
            ca[kf] = load_w_frag(emb_loc + (size_t)p * 128 + kf * 32 + lg * 8);
            wvf[kf] = *(const bf16x8*)&WvTws[(w * 16 + lr) * 128 + kf * 32 + lg * 8];
        }
        f32x4 accw = (f32x4){0.f, 0.f, 0.f, 0.f};
#pragma unroll
        for (int kf = 0; kf < 4; ++kf) accw = MFMA(ca[kf], wvf[kf], accw);
#pragma unroll
        for (int r = 0; r < 4; ++r)
            CWl[swzs(lg * 4 + r, w * 16 + lr)] = (short)f2bfu(accw[r]);
    }
    __syncthreads();

    // ---- P2a: S into regs (wave w -> i-tile w) + CV (wave w -> j-tile w) ----
    f32x4 sacc[8];
    {
        bf16x8 t1f[4];
#pragma unroll
        for (int kf = 0; kf < 4; ++kf)
            t1f[kf] = *(const bf16x8*)&T1l[swz8(w * 16 + lr, kf * 4 + lg)];
#pragma unroll
        for (int jt = 0; jt < 8; ++jt) sacc[jt] = (f32x4){0.f, 0.f, 0.f, 0.f};
#pragma unroll
        for (int jt = 0; jt < 8; ++jt)
#pragma unroll
            for (int kf = 0; kf < 4; ++kf) {
                bf16x8 bj = *(const bf16x8*)&Jl[swz8(jt * 16 + lr, kf * 4 + lg)];
                sacc[jt] = MFMA(t1f[kf], bj, sacc[jt]);
            }
    }
    {
        bf16x8 cwf[4];
#pragma unroll
        for (int kf = 0; kf < 4; ++kf)
            cwf[kf] = *(const bf16x8*)&CWl[swz8(lr, kf * 4 + lg)];
        f32x4 accv = (f32x4){0.f, 0.f, 0.f, 0.f};
#pragma unroll
        for (int kf = 0; kf < 4; ++kf) {
            bf16x8 bj = *(const bf16x8*)&Jl[swz8(w * 16 + lr, kf * 4 + lg)];
            accv = MFMA(cwf[kf], bj, accv);
        }
#pragma unroll
        for (int r = 0; r < 4; ++r) {
            float f = accv[r];
            unsigned short h = f2bfu(f);
            float rem = f - bfu2f(h);
            CVh[swzs(lg * 4 + r, w * 16 + lr)] = (short)h;
            CVm[swzs(lg * 4 + r, w * 16 + lr)] = (short)f2bfu(rem);
        }
    }
    __syncthreads();

    // ---- P2b: softmax -> P (overwrites Jl) ----
    {
        float c0_1 = coef[1] + coef[5];
        float c1_1 = (coef[3] - coef[1]) * 0.01f;
        float c2_1 = (coef[7] - coef[5]) * 0.01f;
        float c0_0 = coef[0] + coef[4];
        float c1_0 = (coef[2] - coef[0]) * 0.01f;
        float c2_0 = (coef[6] - coef[4]) * 0.01f;
#pragma unroll
        for (int r = 0; r < 4; ++r) {
            int ig = w * 16 + lg * 4 + r;
            int mi = (ig < tl) ? 1 : 0;
            float lgv[8];
            int mk[8];
#pragma unroll
            for (int jt = 0; jt < 8; ++jt) {
                int j = jt * 16 + lr;
                mk[jt] = mi & ((j < tl) ? 1 : 0);
                float2 d = *(const float2*)&mat1[((size_t)(b * MM + ig) * MM + j) * 2];
                float cc0 = mk[jt] ? c0_1 : c0_0;
                float cc1 = mk[jt] ? c1_1 : c1_0;
                float cc2 = mk[jt] ? c2_1 : c2_0;
                lgv[jt] = sacc[jt][r] + cc0 + cc1 * d.x + cc2 * d.y;
            }
            float mx = lgv[0];
#pragma unroll
            for (int jt = 1; jt < 8; ++jt) mx = fmaxf(mx, lgv[jt]);
#pragma unroll
            for (int off = 8; off >= 1; off >>= 1) mx = fmaxf(mx, __shfl_xor(mx, off, 64));
            float ee[8], sum = 0.f;
#pragma unroll
            for (int jt = 0; jt < 8; ++jt) { ee[jt] = __expf(lgv[jt] - mx); sum += ee[jt]; }
#pragma unroll
            for (int off = 8; off >= 1; off >>= 1) sum += __shfl_xor(sum, off, 64);
            float inv = 1.0f / sum;
#pragma unroll
            for (int jt = 0; jt < 8; ++jt)
                Jl[swzs(ig, jt * 16 + lr)] = (short)f2bfu(ee[jt] * inv * (float)mk[jt]);
        }
    }
    __syncthreads();

    // ---- P3: G = CV.P^T (wave w -> i-tile w) ; epilogue ; store ----
    {
        bf16x8 cvh[4], cvm[4], bp[4];
#pragma unroll
        for (int kf = 0; kf < 4; ++kf) {
            cvh[kf] = *(const bf16x8*)&CVh[swz8(lr, kf * 4 + lg)];
            cvm[kf] = *(const bf16x8*)&CVm[swz8(lr, kf * 4 + lg)];
            bp[kf]  = *(const bf16x8*)&Jl[swz8(w * 16 + lr, kf * 4 + lg)];
        }
        f32x4 acc = (f32x4){0.f, 0.f, 0.f, 0.f};
#pragma unroll
        for (int kf = 0; kf < 4; ++kf) {
            acc = MFMA(cvh[kf], bp[kf], acc);
            acc = MFMA(cvm[kf], bp[kf], acc);
        }
        int i = w * 16 + lr;
        float4 m2 = *(const float4*)&mat2[(size_t)(b * MM + i) * MM + l0g + lg * 4];
        float wt = tms[i], wb = bsv[i];
        float val[4];
        val[0] = acc[0] * (wt + wb * m2.x);
        val[1] = acc[1] * (wt + wb * m2.y);
        val[2] = acc[2] * (wt + wb * m2.z);
        val[3] = acc[3] * (wt + wb * m2.w);
#pragma unroll
        for (int r = 0; r < 4; ++r) {
            float v = val[r];
            v += __shfl_xor(v, 1, 64);
            v += __shfl_xor(v, 2, 64);
            v += __shfl_xor(v, 4, 64);
            v += __shfl_xor(v, 8, 64);
            if (lr == 0) PART[w][lg * 4 + r] = v;
        }
    }
    __syncthreads();
    if (tid < 16) {
        float s = 0.f;
#pragma unroll
        for (int w8 = 0; w8 < 8; ++w8) s += PART[w8][tid];
        outp[b * MM + l0g + tid] = s;
    }
}

extern "C" void kernel_launch(void* const* d_in, const int* in_sizes, int n_in,
                              void* d_out, int out_size, void* d_ws, size_t ws_size,
                              hipStream_t stream) {
    const int* full_seq = (const int*)d_in[0];
    const int* time_seq = (const int*)d_in[1];
    const int* user     = (const int*)d_in[2];
    const int* posneg   = (const int*)d_in[3];
    const int* traj_len = (const int*)d_in[4];
    const float* mat1   = (const float*)d_in[5];
    const float* mat2   = (const float*)d_in[6];
    const float* vec    = (const float*)d_in[7];
    const float* emb_t  = (const float*)d_in[8];
    const float* emb_u  = (const float*)d_in[9];
    const float* emb_loc= (const float*)d_in[10];
    const float* emb_sl = (const float*)d_in[11];
    const float* emb_su = (const float*)d_in[12];
    const float* emb_tl = (const float*)d_in[13];
    const float* emb_tu = (const float*)d_in[14];
    const float* Wq     = (const float*)d_in[15];
    const float* Wk     = (const float*)d_in[16];
    const float* Wv     = (const float*)d_in[17];

    short* ATws  = (short*)d_ws;
    short* WvTws = ATws + 128 * 128;

    k_prep<<<8, 256, 0, stream>>>(Wq, Wk, Wv, ATws, WvTws);
    k_main<<<dim3(8, 32), 512, 0, stream>>>(full_seq, time_seq, user, posneg, traj_len,
                                            mat1, mat2, vec, emb_t, emb_u, emb_loc,
                                            emb_sl, emb_su, emb_tl, emb_tu,
                                            ATws, WvTws, (float*)d_out);
}